// Round 1
// baseline (326.604 us; speedup 1.0000x reference)
//
#include <hip/hip_runtime.h>
#include <hip/hip_bf16.h>

#define B_ 2
#define T_ 2048
#define E_ 1024
#define H_ 4
#define DK 256
#define DV 512
#define MROWS 4096      // B_*T_
#define LDQKVG 6144     // q(1024) k(1024) v(2048) g(2048)
#define LDOG 2048

typedef __attribute__((ext_vector_type(8))) short short8;
typedef __attribute__((ext_vector_type(4))) float floatx4;

static __device__ __forceinline__ float bf2f(unsigned short u) {
  union { unsigned int i; float f; } x; x.i = ((unsigned int)u) << 16; return x.f;
}
static __device__ __forceinline__ unsigned short f2bf(float f) {
  __hip_bfloat16 h = __float2bfloat16(f);
  return __builtin_bit_cast(unsigned short, h);
}
static __device__ __forceinline__ float load_as_f(const float* p) { return *p; }
static __device__ __forceinline__ float load_as_f(const unsigned short* p) { return bf2f(*p); }

// ---------------- x -> bf16 ----------------
__global__ void __launch_bounds__(256) convx_kernel(const float* __restrict__ x,
                                                    unsigned short* __restrict__ xb) {
  int i = blockIdx.x * 256 + threadIdx.x;   // 524288 threads, 8 elems each
  size_t base = (size_t)i * 8;
  float4 a = *(const float4*)(x + base);
  float4 b = *(const float4*)(x + base + 4);
  short8 o;
  o[0] = (short)f2bf(a.x); o[1] = (short)f2bf(a.y);
  o[2] = (short)f2bf(a.z); o[3] = (short)f2bf(a.w);
  o[4] = (short)f2bf(b.x); o[5] = (short)f2bf(b.y);
  o[6] = (short)f2bf(b.z); o[7] = (short)f2bf(b.w);
  *(short8*)(xb + base) = o;
}

// ---------------- transpose (R x C) -> bf16 (C x R) ----------------
template<typename TIN>
__global__ void __launch_bounds__(256) transpose_bf16_kernel(
    const TIN* __restrict__ in, int ldin, unsigned short* __restrict__ out, int ldout) {
  __shared__ float tile[32][33];
  int c0 = blockIdx.x * 32, r0 = blockIdx.y * 32;
  int tx = threadIdx.x & 31, ty = threadIdx.x >> 5;   // ty 0..7
#pragma unroll
  for (int i = 0; i < 32; i += 8)
    tile[ty + i][tx] = load_as_f(&in[(size_t)(r0 + ty + i) * ldin + c0 + tx]);
  __syncthreads();
#pragma unroll
  for (int i = 0; i < 32; i += 8)
    out[(size_t)(c0 + ty + i) * ldout + r0 + tx] = f2bf(tile[tx][ty + i]);
}

// ---------------- GEMM: C[m][ccol0+n] = sum_k A[m][k] * Bt[n][k] ----------------
// A: M x K bf16 (lda=K), Bt: N x K bf16 (ldb=K). grid (M/128, N/128), 256 thr.
template<bool F32OUT>
__global__ void __launch_bounds__(256) gemm_bt_kernel(
    const unsigned short* __restrict__ A, const unsigned short* __restrict__ Bt,
    void* __restrict__ Cp, int K, int ldc, int ccol0) {
  __shared__ unsigned short As[128 * 32];
  __shared__ unsigned short Bs[128 * 32];
  const int tid = threadIdx.x;
  const int lane = tid & 63;
  const int wid = tid >> 6;
  const int m0 = blockIdx.x * 128;
  const int n0 = blockIdx.y * 128;
  const int wr = (wid >> 1) * 64, wc = (wid & 1) * 64;
  floatx4 acc[4][4];
#pragma unroll
  for (int i = 0; i < 4; i++)
#pragma unroll
    for (int j = 0; j < 4; j++)
#pragma unroll
      for (int r = 0; r < 4; r++) acc[i][j][r] = 0.0f;

  for (int k0 = 0; k0 < K; k0 += 32) {
    __syncthreads();
#pragma unroll
    for (int c = 0; c < 2; ++c) {
      int ci = tid + c * 256;               // 512 chunks of 16B per tile
      int row = ci >> 2, cc = (ci & 3) * 8;
      *(short8*)&As[ci * 8] = *(const short8*)&A[(size_t)(m0 + row) * K + k0 + cc];
      *(short8*)&Bs[ci * 8] = *(const short8*)&Bt[(size_t)(n0 + row) * K + k0 + cc];
    }
    __syncthreads();
    short8 af[4], bfr[4];
#pragma unroll
    for (int mb = 0; mb < 4; mb++)
      af[mb] = *(const short8*)&As[(wr + mb * 16 + (lane & 15)) * 32 + (lane >> 4) * 8];
#pragma unroll
    for (int nb = 0; nb < 4; nb++)
      bfr[nb] = *(const short8*)&Bs[(wc + nb * 16 + (lane & 15)) * 32 + (lane >> 4) * 8];
#pragma unroll
    for (int mb = 0; mb < 4; mb++)
#pragma unroll
      for (int nb = 0; nb < 4; nb++)
        acc[mb][nb] = __builtin_amdgcn_mfma_f32_16x16x32_bf16(af[mb], bfr[nb], acc[mb][nb], 0, 0, 0);
  }
#pragma unroll
  for (int mb = 0; mb < 4; mb++)
#pragma unroll
    for (int nb = 0; nb < 4; nb++)
#pragma unroll
      for (int r = 0; r < 4; r++) {
        int row = m0 + wr + mb * 16 + (lane >> 4) * 4 + r;
        int col = ccol0 + n0 + wc + nb * 16 + (lane & 15);
        float v = acc[mb][nb][r];
        if (F32OUT) ((float*)Cp)[(size_t)row * ldc + col] = v;
        else ((unsigned short*)Cp)[(size_t)row * ldc + col] = f2bf(v);
      }
}

// ---------------- RoPE in place on q,k (+ q scale) ----------------
__global__ void __launch_bounds__(256) rope_kernel(unsigned short* __restrict__ qkvg) {
  int idx = blockIdx.x * 256 + threadIdx.x;   // 4096*4*128
  int j = idx & 127;
  int h = (idx >> 7) & 3;
  int row = idx >> 9;
  int t = row & (T_ - 1);
  float invf = exp2f(-(float)j * (13.287712379549449f / 128.0f));  // 10000^(-j/128)
  float ang = (float)t * invf;
  float c = cosf(ang), s = sinf(ang);
  size_t base = (size_t)row * LDQKVG + h * DK + j;
  float q1 = bf2f(qkvg[base]), q2 = bf2f(qkvg[base + 128]);
  float k1 = bf2f(qkvg[base + E_]), k2 = bf2f(qkvg[base + E_ + 128]);
  qkvg[base]            = f2bf((q1 * c - q2 * s) * 0.0625f);
  qkvg[base + 128]      = f2bf((q2 * c + q1 * s) * 0.0625f);
  qkvg[base + E_]       = f2bf(k1 * c - k2 * s);
  qkvg[base + E_ + 128] = f2bf(k2 * c + k1 * s);
}

// ---------------- retention core + RMS-norm + gate, fused ----------------
// grid 256: bh = bx>>5 (b=bh>>2,h=bh&3), row-tile tj = bx&31 (64 rows).
// 4 waves, wave owns 16 rows. KV staged in 32-row blocks.
__global__ void __launch_bounds__(256) retention_kernel(
    const unsigned short* __restrict__ qkvg, const unsigned short* __restrict__ vT,
    const float* __restrict__ gnw, unsigned short* __restrict__ og) {
  __shared__ unsigned short k_lds[32 * 256];   // 16KB, 512B rows, xor-swizzled
  __shared__ unsigned short v_lds[512 * 32];   // 32KB, 64B rows,  xor-swizzled
  __shared__ unsigned short s_lds[4 * 16 * 32];// 4KB, per-wave 1KB
  const int tid = threadIdx.x, lane = tid & 63, wid = tid >> 6;
  const int bx = blockIdx.x;
  const int bh = bx >> 5, tj = bx & 31;
  const int b = bh >> 2, h = bh & 3;
  const int i0 = tj * 64;
  const int rowbase = i0 + wid * 16;
  const float log2g = log2f(1.0f - exp2f(-5.0f - (float)h));

  short8 qf[8];
  {
    int qrow = b * T_ + rowbase + (lane & 15);
    const unsigned short* qp = qkvg + (size_t)qrow * LDQKVG + h * DK + (lane >> 4) * 8;
#pragma unroll
    for (int kk = 0; kk < 8; kk++) qf[kk] = *(const short8*)(qp + kk * 32);
  }
  floatx4 oacc[32];
#pragma unroll
  for (int i = 0; i < 32; i++)
#pragma unroll
    for (int r = 0; r < 4; r++) oacc[i][r] = 0.0f;

  const int nsb = (i0 + 64) / 32;
  for (int sb = 0; sb < nsb; ++sb) {
    const int s0 = sb * 32;
    __syncthreads();
    // stage k block: 32 x 256, 1024 x16B chunks
#pragma unroll
    for (int c = 0; c < 4; c++) {
      int ci = tid + c * 256;
      int row = ci >> 5, cc = ci & 31;
      short8 v = *(const short8*)&qkvg[(size_t)(b * T_ + s0 + row) * LDQKVG + E_ + h * DK + cc * 8];
      int byte = (row * 512 + cc * 16) ^ ((row & 7) << 4);
      *(short8*)((char*)k_lds + byte) = v;
    }
    // stage vT block: 512 x 32, 2048 x16B chunks
#pragma unroll
    for (int c = 0; c < 8; c++) {
      int ci = tid + c * 256;
      int dv = ci >> 2, cc = ci & 3;
      short8 v = *(const short8*)&vT[(size_t)(h * DV + dv) * MROWS + b * T_ + s0 + cc * 8];
      int byte = (dv * 64 + cc * 16) ^ ((dv & 3) << 4);
      *(short8*)((char*)v_lds + byte) = v;
    }
    __syncthreads();
    // phase 1: scores (16 rows x 32 cols per wave), decay, bf16 -> s_lds
#pragma unroll
    for (int cb = 0; cb < 2; ++cb) {
      floatx4 f;
#pragma unroll
      for (int r = 0; r < 4; r++) f[r] = 0.0f;
#pragma unroll
      for (int kk = 0; kk < 8; kk++) {
        int row = cb * 16 + (lane & 15);
        int byte = (row * 512 + kk * 64 + (lane >> 4) * 16) ^ ((row & 7) << 4);
        short8 kf = *(const short8*)((char*)k_lds + byte);
        f = __builtin_amdgcn_mfma_f32_16x16x32_bf16(qf[kk], kf, f, 0, 0, 0);
      }
#pragma unroll
      for (int r = 0; r < 4; r++) {
        int lr = (lane >> 4) * 4 + r;
        int qrow = rowbase + lr;
        int scol = s0 + cb * 16 + (lane & 15);
        int n = qrow - scol;
        float val = (n >= 0) ? f[r] * exp2f((float)n * log2g) : 0.0f;
        int cc = cb * 16 + (lane & 15);
        int byte = wid * 1024 + lr * 64 + ((cc * 2) ^ ((lr & 3) << 4));
        *(unsigned short*)((char*)s_lds + byte) = f2bf(val);
      }
    }
    // phase 2: o += S @ v  (K = 32)
    short8 af;
    {
      int row = lane & 15;
      int byte = wid * 1024 + row * 64 + (((lane >> 4) * 16) ^ ((row & 3) << 4));
      af = *(const short8*)((char*)s_lds + byte);
    }
#pragma unroll
    for (int cb2 = 0; cb2 < 32; ++cb2) {
      int dv = cb2 * 16 + (lane & 15);
      int byte = (dv * 64 + (lane >> 4) * 16) ^ ((dv & 3) << 4);
      short8 vf = *(const short8*)((char*)v_lds + byte);
      oacc[cb2] = __builtin_amdgcn_mfma_f32_16x16x32_bf16(af, vf, oacc[cb2], 0, 0, 0);
    }
  }
  // epilogue: RMS over Dv per row, * gn_weight * g -> og (bf16)
#pragma unroll
  for (int r = 0; r < 4; r++) {
    float ss = 0.f;
#pragma unroll
    for (int cb2 = 0; cb2 < 32; cb2++) { float x = oacc[cb2][r]; ss += x * x; }
    ss += __shfl_xor(ss, 1, 64);
    ss += __shfl_xor(ss, 2, 64);
    ss += __shfl_xor(ss, 4, 64);
    ss += __shfl_xor(ss, 8, 64);
    float inv = rsqrtf(ss * (1.0f / 512.0f) + 1e-5f);
    int qrow = rowbase + (lane >> 4) * 4 + r;
    size_t growbase = (size_t)(b * T_ + qrow) * LDQKVG + 4096 + h * DV;
    size_t orowbase = (size_t)(b * T_ + qrow) * LDOG + h * DV;
#pragma unroll
    for (int cb2 = 0; cb2 < 32; cb2++) {
      int col = cb2 * 16 + (lane & 15);
      float gv = bf2f(qkvg[growbase + col]);
      og[orowbase + col] = f2bf(oacc[cb2][r] * inv * gnw[col] * gv);
    }
  }
}

extern "C" void kernel_launch(void* const* d_in, const int* in_sizes, int n_in,
                              void* d_out, int out_size, void* d_ws, size_t ws_size,
                              hipStream_t stream) {
  const float* x   = (const float*)d_in[0];
  const float* Wq  = (const float*)d_in[1];
  const float* Wk  = (const float*)d_in[2];
  const float* Wv  = (const float*)d_in[3];
  const float* Wg  = (const float*)d_in[4];
  const float* Wo  = (const float*)d_in[5];
  const float* gnw = (const float*)d_in[6];
  float* out = (float*)d_out;

  char* ws = (char*)d_ws;
  size_t off = 0;
  auto alloc = [&](size_t bytes) { char* p = ws + off; off += (bytes + 255) & ~(size_t)255; return p; };
  unsigned short* xb   = (unsigned short*)alloc((size_t)MROWS * E_ * 2);
  unsigned short* WqT  = (unsigned short*)alloc((size_t)1024 * 1024 * 2);
  unsigned short* WkT  = (unsigned short*)alloc((size_t)1024 * 1024 * 2);
  unsigned short* WvT  = (unsigned short*)alloc((size_t)2048 * 1024 * 2);
  unsigned short* WgT  = (unsigned short*)alloc((size_t)2048 * 1024 * 2);
  unsigned short* WoT  = (unsigned short*)alloc((size_t)1024 * 2048 * 2);
  unsigned short* qkvg = (unsigned short*)alloc((size_t)MROWS * LDQKVG * 2);
  unsigned short* vT   = (unsigned short*)alloc((size_t)2048 * MROWS * 2);
  unsigned short* og   = (unsigned short*)alloc((size_t)MROWS * LDOG * 2);

  convx_kernel<<<2048, 256, 0, stream>>>(x, xb);

  transpose_bf16_kernel<float><<<dim3(32, 32), 256, 0, stream>>>(Wq, 1024, WqT, 1024);
  transpose_bf16_kernel<float><<<dim3(32, 32), 256, 0, stream>>>(Wk, 1024, WkT, 1024);
  transpose_bf16_kernel<float><<<dim3(64, 32), 256, 0, stream>>>(Wv, 2048, WvT, 1024);
  transpose_bf16_kernel<float><<<dim3(64, 32), 256, 0, stream>>>(Wg, 2048, WgT, 1024);
  transpose_bf16_kernel<float><<<dim3(32, 64), 256, 0, stream>>>(Wo, 1024, WoT, 2048);

  gemm_bt_kernel<false><<<dim3(32, 8),  256, 0, stream>>>(xb, WqT, qkvg, 1024, LDQKVG, 0);
  gemm_bt_kernel<false><<<dim3(32, 8),  256, 0, stream>>>(xb, WkT, qkvg, 1024, LDQKVG, 1024);
  gemm_bt_kernel<false><<<dim3(32, 16), 256, 0, stream>>>(xb, WvT, qkvg, 1024, LDQKVG, 2048);
  gemm_bt_kernel<false><<<dim3(32, 16), 256, 0, stream>>>(xb, WgT, qkvg, 1024, LDQKVG, 4096);

  rope_kernel<<<8192, 256, 0, stream>>>(qkvg);

  // v block (4096 x 2048 at col 2048) -> vT (2048 x 4096)
  transpose_bf16_kernel<unsigned short><<<dim3(64, 128), 256, 0, stream>>>(qkvg + 2048, LDQKVG, vT, MROWS);

  retention_kernel<<<256, 256, 0, stream>>>(qkvg, vT, gnw, og);

  gemm_bt_kernel<true><<<dim3(32, 8), 256, 0, stream>>>(og, WoT, out, 2048, E_, 0);
}

// Round 2
// 258.404 us; speedup vs baseline: 1.2639x; 1.2639x over previous
//
#include <hip/hip_runtime.h>
#include <hip/hip_bf16.h>

#define B_ 2
#define T_ 2048
#define E_ 1024
#define DK 256
#define DV 512
#define MROWS 4096      // B_*T_
#define LDQKVG 6144     // q(1024) k(1024) v(2048) g(2048)
#define LDOG 2048

typedef __attribute__((ext_vector_type(8))) short short8;
typedef __attribute__((ext_vector_type(4))) float floatx4;

typedef __attribute__((address_space(3))) unsigned as3_u32;
typedef const __attribute__((address_space(1))) unsigned as1_u32;

// async global -> LDS, 16B per lane; ldst must be wave-uniform, gsrc per-lane.
static __device__ __forceinline__ void gld_lds16(const unsigned short* gsrc, unsigned short* ldst) {
  __builtin_amdgcn_global_load_lds((as1_u32*)gsrc, (as3_u32*)ldst, 16, 0, 0);
}

static __device__ __forceinline__ float bf2f(unsigned short u) {
  union { unsigned int i; float f; } x; x.i = ((unsigned int)u) << 16; return x.f;
}
static __device__ __forceinline__ unsigned short f2bf(float f) {
  __hip_bfloat16 h = __float2bfloat16(f);
  return __builtin_bit_cast(unsigned short, h);
}
static __device__ __forceinline__ float load_as_f(const float* p) { return *p; }
static __device__ __forceinline__ float load_as_f(const unsigned short* p) { return bf2f(*p); }

// ---------------- x -> bf16 ----------------
__global__ void __launch_bounds__(256) convx_kernel(const float* __restrict__ x,
                                                    unsigned short* __restrict__ xb) {
  int i = blockIdx.x * 256 + threadIdx.x;
  size_t base = (size_t)i * 8;
  float4 a = *(const float4*)(x + base);
  float4 b = *(const float4*)(x + base + 4);
  short8 o;
  o[0] = (short)f2bf(a.x); o[1] = (short)f2bf(a.y);
  o[2] = (short)f2bf(a.z); o[3] = (short)f2bf(a.w);
  o[4] = (short)f2bf(b.x); o[5] = (short)f2bf(b.y);
  o[6] = (short)f2bf(b.z); o[7] = (short)f2bf(b.w);
  *(short8*)(xb + base) = o;
}

// ---------------- transpose (R x C) -> bf16 (C x R) ----------------
template<typename TIN>
__global__ void __launch_bounds__(256) transpose_bf16_kernel(
    const TIN* __restrict__ in, int ldin, unsigned short* __restrict__ out, int ldout) {
  __shared__ float tile[32][33];
  int c0 = blockIdx.x * 32, r0 = blockIdx.y * 32;
  int tx = threadIdx.x & 31, ty = threadIdx.x >> 5;
#pragma unroll
  for (int i = 0; i < 32; i += 8)
    tile[ty + i][tx] = load_as_f(&in[(size_t)(r0 + ty + i) * ldin + c0 + tx]);
  __syncthreads();
#pragma unroll
  for (int i = 0; i < 32; i += 8)
    out[(size_t)(c0 + ty + i) * ldout + r0 + tx] = f2bf(tile[tx][ty + i]);
}

// ---------------- GEMM (m97-style global_load_lds staging) ----------------
// C[m][ccol0+n] = sum_k A[m][k] * Bt[n][k]; A: MxK, Bt: NxK, bf16. grid (M/128,N/128).
template<bool F32OUT>
__global__ void __launch_bounds__(256) gemm_bt_kernel(
    const unsigned short* __restrict__ A, const unsigned short* __restrict__ Bt,
    void* __restrict__ Cp, int K, int ldc, int ccol0) {
  __shared__ unsigned short As[128 * 32];
  __shared__ unsigned short Bs[128 * 32];
  const int tid = threadIdx.x;
  const int lane = tid & 63;
  const int wid = tid >> 6;
  const int m0 = blockIdx.x * 128;
  const int n0 = blockIdx.y * 128;
  const int wr = (wid >> 1) * 64, wc = (wid & 1) * 64;
  floatx4 acc[4][4];
#pragma unroll
  for (int i = 0; i < 4; i++)
#pragma unroll
    for (int j = 0; j < 4; j++)
      acc[i][j] = (floatx4){0.f, 0.f, 0.f, 0.f};

  for (int k0 = 0; k0 < K; k0 += 32) {
    __syncthreads();
#pragma unroll
    for (int j = 0; j < 2; ++j) {
      int ci = (wid * 2 + j) * 64 + lane;       // 512 chunks of 16B per tile
      int row = ci >> 2, cc = (ci & 3) * 8;
      gld_lds16(&A[(size_t)(m0 + row) * K + k0 + cc], &As[(wid * 2 + j) * 64 * 8]);
      gld_lds16(&Bt[(size_t)(n0 + row) * K + k0 + cc], &Bs[(wid * 2 + j) * 64 * 8]);
    }
    __syncthreads();   // compiler drains vmcnt before barrier
    short8 af[4], bfr[4];
#pragma unroll
    for (int mb = 0; mb < 4; mb++)
      af[mb] = *(const short8*)&As[(wr + mb * 16 + (lane & 15)) * 32 + (lane >> 4) * 8];
#pragma unroll
    for (int nb = 0; nb < 4; nb++)
      bfr[nb] = *(const short8*)&Bs[(wc + nb * 16 + (lane & 15)) * 32 + (lane >> 4) * 8];
#pragma unroll
    for (int mb = 0; mb < 4; mb++)
#pragma unroll
      for (int nb = 0; nb < 4; nb++)
        acc[mb][nb] = __builtin_amdgcn_mfma_f32_16x16x32_bf16(af[mb], bfr[nb], acc[mb][nb], 0, 0, 0);
  }
#pragma unroll
  for (int mb = 0; mb < 4; mb++)
#pragma unroll
    for (int nb = 0; nb < 4; nb++)
#pragma unroll
      for (int r = 0; r < 4; r++) {
        int row = m0 + wr + mb * 16 + (lane >> 4) * 4 + r;
        int col = ccol0 + n0 + wc + nb * 16 + (lane & 15);
        float v = acc[mb][nb][r];
        if (F32OUT) ((float*)Cp)[(size_t)row * ldc + col] = v;
        else ((unsigned short*)Cp)[(size_t)row * ldc + col] = f2bf(v);
      }
}

// ---------------- RoPE in place on q,k (+ q scale) ----------------
__global__ void __launch_bounds__(256) rope_kernel(unsigned short* __restrict__ qkvg) {
  int idx = blockIdx.x * 256 + threadIdx.x;
  int j = idx & 127;
  int h = (idx >> 7) & 3;
  int row = idx >> 9;
  int t = row & (T_ - 1);
  float invf = exp2f(-(float)j * (13.287712379549449f / 128.0f));
  float ang = (float)t * invf;
  float c = cosf(ang), s = sinf(ang);
  size_t base = (size_t)row * LDQKVG + h * DK + j;
  float q1 = bf2f(qkvg[base]), q2 = bf2f(qkvg[base + 128]);
  float k1 = bf2f(qkvg[base + E_]), k2 = bf2f(qkvg[base + E_ + 128]);
  qkvg[base]            = f2bf((q1 * c - q2 * s) * 0.0625f);
  qkvg[base + 128]      = f2bf((q2 * c + q1 * s) * 0.0625f);
  qkvg[base + E_]       = f2bf(k1 * c - k2 * s);
  qkvg[base + E_ + 128] = f2bf(k2 * c + k1 * s);
}

// ---------------- retention core + RMS-norm + gate, fused ----------------
// grid 256 blocks: bh = bid&7 (XCD-pinned), pair index p = bid>>3.
// Block processes 32-row tile p then tile 63-p: constant 65 KV-steps.
// 4 waves: rh = wid&1 (16-row half), dh = wid>>1 (256-col Dv half / score col half).
// K/V double-buffered in LDS via source-swizzled global_load_lds.
__global__ void __launch_bounds__(256) retention_kernel(
    const unsigned short* __restrict__ qkvg, const unsigned short* __restrict__ vT,
    const float* __restrict__ gnw, unsigned short* __restrict__ og) {
  __shared__ unsigned short k_lds[2][32 * 256];   // 2 x 16KB
  __shared__ unsigned short v_lds[2][512 * 32];   // 2 x 32KB
  __shared__ unsigned short s_lds[2][16 * 32];    // per rowhalf, 1KB each
  __shared__ float rms_lds[32][2];
  const int tid = threadIdx.x, lane = tid & 63, wid = tid >> 6;
  const int rh = wid & 1, dh = wid >> 1;
  const int bh = blockIdx.x & 7, p = blockIdx.x >> 3;
  const int b = bh >> 2, h = bh & 3;
  const float log2g = log2f(1.0f - exp2f(-5.0f - (float)h));
  const unsigned short* kbase = qkvg + (size_t)b * T_ * LDQKVG + E_ + h * DK;
  const unsigned short* vbase = vT + (size_t)h * DV * MROWS + b * T_;

  // stage KV block sb into buffer buf (async; drained at next barrier)
  auto stage = [&](int buf, int sb) {
    int s0 = sb * 32;
#pragma unroll
    for (int j = 0; j < 4; ++j) {               // K: 32 rows x 256, 1024 chunks
      int ci = (wid * 4 + j) * 64 + lane;
      int row = ci >> 5, c = ci & 31;
      int cs = c ^ (row & 7);                   // inverse swizzle on SOURCE
      gld_lds16(kbase + (size_t)(s0 + row) * LDQKVG + cs * 8,
                &k_lds[buf][(wid * 4 + j) * 64 * 8]);
    }
#pragma unroll
    for (int j = 0; j < 8; ++j) {               // V: 512 dv x 32, 2048 chunks
      int ci = (wid * 8 + j) * 64 + lane;
      int dv = ci >> 2, c = ci & 3;
      int cs = c ^ ((dv ^ (dv >> 2)) & 3);
      gld_lds16(vbase + (size_t)dv * MROWS + s0 + cs * 8,
                &v_lds[buf][(wid * 8 + j) * 64 * 8]);
    }
  };

#pragma unroll 1
  for (int half = 0; half < 2; ++half) {
    const int tt = half == 0 ? p : 63 - p;
    const int r0 = tt * 32;
    const int nsb = tt + 1;

    short8 qf[8];
    {
      int qrow = b * T_ + r0 + rh * 16 + (lane & 15);
      const unsigned short* qp = qkvg + (size_t)qrow * LDQKVG + h * DK + (lane >> 4) * 8;
#pragma unroll
      for (int kk = 0; kk < 8; kk++) qf[kk] = *(const short8*)(qp + kk * 32);
    }
    floatx4 oacc[16];
#pragma unroll
    for (int i = 0; i < 16; i++) oacc[i] = (floatx4){0.f, 0.f, 0.f, 0.f};

    stage(0, 0);
#pragma unroll 1
    for (int sb = 0; sb < nsb; ++sb) {
      const int cur = sb & 1;
      __syncthreads();                           // staging of cur done; prev S consumed
      // phase 1: S[rh half 16 rows][dh half 16 cols], K = 256
      floatx4 f = (floatx4){0.f, 0.f, 0.f, 0.f};
      const int scol_l = dh * 16 + (lane & 15);
#pragma unroll
      for (int kk = 0; kk < 8; kk++) {
        int c = (kk * 4 + (lane >> 4)) ^ (scol_l & 7);
        short8 kf = *(const short8*)&k_lds[cur][scol_l * 256 + c * 8];
        f = __builtin_amdgcn_mfma_f32_16x16x32_bf16(qf[kk], kf, f, 0, 0, 0);
      }
      const int s0 = sb * 32;
#pragma unroll
      for (int r = 0; r < 4; ++r) {
        int lr = (lane >> 4) * 4 + r;
        int qrow_h = r0 + rh * 16 + lr;
        int scol = s0 + dh * 16 + (lane & 15);
        int n = qrow_h - scol;
        float val = (n >= 0) ? f[r] * exp2f((float)n * log2g) : 0.0f;
        int cc = dh * 16 + (lane & 15);
        int byte = lr * 64 + ((cc * 2) ^ ((lr & 3) << 4));
        *(unsigned short*)((char*)s_lds[rh] + byte) = f2bf(val);
      }
      __syncthreads();                           // S ready
      if (sb + 1 < nsb) stage(cur ^ 1, sb + 1);  // prefetch overlaps phase 2
      // phase 2: O[16 rows][dh*256 .. +256] += S @ V
      short8 af;
      {
        int row = lane & 15;
        int byte = row * 64 + (((lane >> 4) * 16) ^ ((row & 3) << 4));
        af = *(const short8*)((char*)s_lds[rh] + byte);
      }
#pragma unroll
      for (int nb = 0; nb < 16; ++nb) {
        int dv = dh * 256 + nb * 16 + (lane & 15);
        int c = (lane >> 4) ^ ((dv ^ (dv >> 2)) & 3);
        short8 vf = *(const short8*)&v_lds[cur][dv * 32 + c * 8];
        oacc[nb] = __builtin_amdgcn_mfma_f32_16x16x32_bf16(af, vf, oacc[nb], 0, 0, 0);
      }
    }
    // epilogue: cross-dh RMS reduce, then * gn_weight * g -> og
    float ssp[4];
#pragma unroll
    for (int r = 0; r < 4; ++r) {
      float ss = 0.f;
#pragma unroll
      for (int nb = 0; nb < 16; nb++) { float xv = oacc[nb][r]; ss += xv * xv; }
      ss += __shfl_xor(ss, 1, 64);
      ss += __shfl_xor(ss, 2, 64);
      ss += __shfl_xor(ss, 4, 64);
      ss += __shfl_xor(ss, 8, 64);
      ssp[r] = ss;
    }
    if ((lane & 15) == 0) {
#pragma unroll
      for (int r = 0; r < 4; ++r)
        rms_lds[rh * 16 + (lane >> 4) * 4 + r][dh] = ssp[r];
    }
    __syncthreads();
#pragma unroll
    for (int r = 0; r < 4; ++r) {
      int lrow = rh * 16 + (lane >> 4) * 4 + r;
      float tot = rms_lds[lrow][0] + rms_lds[lrow][1];
      float inv = rsqrtf(tot * (1.0f / 512.0f) + 1e-5f);
      int qrow = b * T_ + r0 + rh * 16 + (lane >> 4) * 4 + r;
      size_t growbase = (size_t)qrow * LDQKVG + 4096 + h * DV + dh * 256;
      size_t orowbase = (size_t)qrow * LDOG + h * DV + dh * 256;
#pragma unroll
      for (int nb = 0; nb < 16; nb++) {
        int col = nb * 16 + (lane & 15);
        float gv = bf2f(qkvg[growbase + col]);
        og[orowbase + col] = f2bf(oacc[nb][r] * inv * gnw[dh * 256 + col] * gv);
      }
    }
    __syncthreads();                             // protect LDS reuse across tiles
  }
}

extern "C" void kernel_launch(void* const* d_in, const int* in_sizes, int n_in,
                              void* d_out, int out_size, void* d_ws, size_t ws_size,
                              hipStream_t stream) {
  const float* x   = (const float*)d_in[0];
  const float* Wq  = (const float*)d_in[1];
  const float* Wk  = (const float*)d_in[2];
  const float* Wv  = (const float*)d_in[3];
  const float* Wg  = (const float*)d_in[4];
  const float* Wo  = (const float*)d_in[5];
  const float* gnw = (const float*)d_in[6];
  float* out = (float*)d_out;

  char* ws = (char*)d_ws;
  size_t off = 0;
  auto alloc = [&](size_t bytes) { char* p = ws + off; off += (bytes + 255) & ~(size_t)255; return p; };
  unsigned short* xb    = (unsigned short*)alloc((size_t)MROWS * E_ * 2);
  unsigned short* WallT = (unsigned short*)alloc((size_t)6144 * 1024 * 2);  // WqT|WkT|WvT|WgT stacked
  unsigned short* WoT   = (unsigned short*)alloc((size_t)1024 * 2048 * 2);
  unsigned short* qkvg  = (unsigned short*)alloc((size_t)MROWS * LDQKVG * 2);
  unsigned short* vT    = (unsigned short*)alloc((size_t)2048 * MROWS * 2);
  unsigned short* og    = (unsigned short*)alloc((size_t)MROWS * LDOG * 2);

  convx_kernel<<<2048, 256, 0, stream>>>(x, xb);

  transpose_bf16_kernel<float><<<dim3(32, 32), 256, 0, stream>>>(Wq, 1024, WallT, 1024);
  transpose_bf16_kernel<float><<<dim3(32, 32), 256, 0, stream>>>(Wk, 1024, WallT + (size_t)1024 * 1024, 1024);
  transpose_bf16_kernel<float><<<dim3(64, 32), 256, 0, stream>>>(Wv, 2048, WallT + (size_t)2048 * 1024, 1024);
  transpose_bf16_kernel<float><<<dim3(64, 32), 256, 0, stream>>>(Wg, 2048, WallT + (size_t)4096 * 1024, 1024);
  transpose_bf16_kernel<float><<<dim3(32, 64), 256, 0, stream>>>(Wo, 1024, WoT, 2048);

  // fused q|k|v|g projection: 4096 x 6144 x 1024
  gemm_bt_kernel<false><<<dim3(32, 48), 256, 0, stream>>>(xb, WallT, qkvg, 1024, LDQKVG, 0);

  rope_kernel<<<8192, 256, 0, stream>>>(qkvg);

  // v block (4096 x 2048 at col 2048) -> vT (2048 x 4096)
  transpose_bf16_kernel<unsigned short><<<dim3(64, 128), 256, 0, stream>>>(qkvg + 2048, LDQKVG, vT, MROWS);

  retention_kernel<<<256, 256, 0, stream>>>(qkvg, vT, gnw, og);

  gemm_bt_kernel<true><<<dim3(32, 8), 256, 0, stream>>>(og, WoT, out, 2048, E_, 0);
}

// Round 3
// 240.716 us; speedup vs baseline: 1.3568x; 1.0735x over previous
//
#include <hip/hip_runtime.h>
#include <hip/hip_bf16.h>

#define B_ 2
#define T_ 2048
#define E_ 1024
#define DK 256
#define DV 512
#define MROWS 4096      // B_*T_
#define LDQKVG 6144     // q(1024) k(1024) v(2048) g(2048)
#define LDOG 2048

typedef __attribute__((ext_vector_type(8))) short short8;
typedef __attribute__((ext_vector_type(4))) float floatx4;

typedef __attribute__((address_space(3))) unsigned as3_u32;
typedef const __attribute__((address_space(1))) unsigned as1_u32;

static __device__ __forceinline__ void gld_lds16(const unsigned short* gsrc, unsigned short* ldst) {
  __builtin_amdgcn_global_load_lds((as1_u32*)gsrc, (as3_u32*)ldst, 16, 0, 0);
}

static __device__ __forceinline__ float bf2f(unsigned short u) {
  union { unsigned int i; float f; } x; x.i = ((unsigned int)u) << 16; return x.f;
}
static __device__ __forceinline__ unsigned short f2bf(float f) {
  __hip_bfloat16 h = __float2bfloat16(f);
  return __builtin_bit_cast(unsigned short, h);
}
static __device__ __forceinline__ float load_as_f(const float* p) { return *p; }
static __device__ __forceinline__ float load_as_f(const unsigned short* p) { return bf2f(*p); }

// ---------------- x -> bf16 ----------------
__global__ void __launch_bounds__(256) convx_kernel(const float* __restrict__ x,
                                                    unsigned short* __restrict__ xb) {
  int i = blockIdx.x * 256 + threadIdx.x;
  size_t base = (size_t)i * 8;
  float4 a = *(const float4*)(x + base);
  float4 b = *(const float4*)(x + base + 4);
  short8 o;
  o[0] = (short)f2bf(a.x); o[1] = (short)f2bf(a.y);
  o[2] = (short)f2bf(a.z); o[3] = (short)f2bf(a.w);
  o[4] = (short)f2bf(b.x); o[5] = (short)f2bf(b.y);
  o[6] = (short)f2bf(b.z); o[7] = (short)f2bf(b.w);
  *(short8*)(xb + base) = o;
}

// ---------------- transpose (R x C) -> bf16 (C x R) ----------------
template<typename TIN>
__global__ void __launch_bounds__(256) transpose_bf16_kernel(
    const TIN* __restrict__ in, int ldin, unsigned short* __restrict__ out, int ldout) {
  __shared__ float tile[32][33];
  int c0 = blockIdx.x * 32, r0 = blockIdx.y * 32;
  int tx = threadIdx.x & 31, ty = threadIdx.x >> 5;
#pragma unroll
  for (int i = 0; i < 32; i += 8)
    tile[ty + i][tx] = load_as_f(&in[(size_t)(r0 + ty + i) * ldin + c0 + tx]);
  __syncthreads();
#pragma unroll
  for (int i = 0; i < 32; i += 8)
    out[(size_t)(c0 + ty + i) * ldout + r0 + tx] = f2bf(tile[tx][ty + i]);
}

// ---------------- GEMM: C[m][ccol0+n] = sum_k A[m][k]*Bt[n][k] ----------------
// MTILE x 128 tile, 4 waves, global_load_lds staging.
template<int MTILE, bool F32OUT>
__global__ void __launch_bounds__(256) gemm_bt_kernel(
    const unsigned short* __restrict__ A, const unsigned short* __restrict__ Bt,
    void* __restrict__ Cp, int K, int ldc, int ccol0) {
  __shared__ unsigned short As[MTILE * 32];
  __shared__ unsigned short Bs[128 * 32];
  constexpr int MB = MTILE / 32;          // 16-row acc blocks per wave
  constexpr int AJ = MTILE / 64;          // A stage chunk-groups per wave
  const int tid = threadIdx.x;
  const int lane = tid & 63;
  const int wid = tid >> 6;
  const int m0 = blockIdx.x * MTILE;
  const int n0 = blockIdx.y * 128;
  const int wr = (wid >> 1) * (MTILE / 2), wc = (wid & 1) * 64;
  floatx4 acc[MB][4];
#pragma unroll
  for (int i = 0; i < MB; i++)
#pragma unroll
    for (int j = 0; j < 4; j++)
      acc[i][j] = (floatx4){0.f, 0.f, 0.f, 0.f};

  for (int k0 = 0; k0 < K; k0 += 32) {
    __syncthreads();
#pragma unroll
    for (int j = 0; j < AJ; ++j) {
      int ci = (wid * AJ + j) * 64 + lane;
      int row = ci >> 2, cc = (ci & 3) * 8;
      gld_lds16(&A[(size_t)(m0 + row) * K + k0 + cc], &As[(wid * AJ + j) * 512]);
    }
#pragma unroll
    for (int j = 0; j < 2; ++j) {
      int ci = (wid * 2 + j) * 64 + lane;
      int row = ci >> 2, cc = (ci & 3) * 8;
      gld_lds16(&Bt[(size_t)(n0 + row) * K + k0 + cc], &Bs[(wid * 2 + j) * 512]);
    }
    __syncthreads();
    short8 af[MB], bfr[4];
#pragma unroll
    for (int mb = 0; mb < MB; mb++)
      af[mb] = *(const short8*)&As[(wr + mb * 16 + (lane & 15)) * 32 + (lane >> 4) * 8];
#pragma unroll
    for (int nb = 0; nb < 4; nb++)
      bfr[nb] = *(const short8*)&Bs[(wc + nb * 16 + (lane & 15)) * 32 + (lane >> 4) * 8];
#pragma unroll
    for (int mb = 0; mb < MB; mb++)
#pragma unroll
      for (int nb = 0; nb < 4; nb++)
        acc[mb][nb] = __builtin_amdgcn_mfma_f32_16x16x32_bf16(af[mb], bfr[nb], acc[mb][nb], 0, 0, 0);
  }
#pragma unroll
  for (int mb = 0; mb < MB; mb++)
#pragma unroll
    for (int nb = 0; nb < 4; nb++)
#pragma unroll
      for (int r = 0; r < 4; r++) {
        int row = m0 + wr + mb * 16 + (lane >> 4) * 4 + r;
        int col = ccol0 + n0 + wc + nb * 16 + (lane & 15);
        float v = acc[mb][nb][r];
        if (F32OUT) ((float*)Cp)[(size_t)row * ldc + col] = v;
        else ((unsigned short*)Cp)[(size_t)row * ldc + col] = f2bf(v);
      }
}

// ---------------- RoPE in place on q,k (+ q scale) ----------------
__global__ void __launch_bounds__(256) rope_kernel(unsigned short* __restrict__ qkvg) {
  int idx = blockIdx.x * 256 + threadIdx.x;
  int j = idx & 127;
  int h = (idx >> 7) & 3;
  int row = idx >> 9;
  int t = row & (T_ - 1);
  float invf = exp2f(-(float)j * (13.287712379549449f / 128.0f));
  float ang = (float)t * invf;
  float c = cosf(ang), s = sinf(ang);
  size_t base = (size_t)row * LDQKVG + h * DK + j;
  float q1 = bf2f(qkvg[base]), q2 = bf2f(qkvg[base + 128]);
  float k1 = bf2f(qkvg[base + E_]), k2 = bf2f(qkvg[base + E_ + 128]);
  qkvg[base]            = f2bf((q1 * c - q2 * s) * 0.0625f);
  qkvg[base + 128]      = f2bf((q2 * c + q1 * s) * 0.0625f);
  qkvg[base + E_]       = f2bf(k1 * c - k2 * s);
  qkvg[base + E_ + 128] = f2bf(k2 * c + k1 * s);
}

// ---------------- retention core (dv-split) + gate, partial-RMS ----------------
// grid 512: bh = bid&7 (XCD pin), dvh = (bid>>3)&1 (256-dv half), p = bid>>4.
// Block does 32-row tiles p and 63-p (constant 65 KV-steps).
// 4 waves: rh = wid&1 (16-row half), dh = wid>>1 (score col half + 128-dv quarter).
// LDS ~67KB -> 2 blocks/CU. og gets o*gnw*g (unnormalized); ssbuf gets partial sums.
__global__ void __launch_bounds__(256) retention_kernel(
    const unsigned short* __restrict__ qkvg, const unsigned short* __restrict__ vT,
    const float* __restrict__ gnw, unsigned short* __restrict__ og,
    float* __restrict__ ssbuf) {
  __shared__ unsigned short k_lds[2][32 * 256];   // 2 x 16KB
  __shared__ unsigned short v_lds[2][256 * 32];   // 2 x 16KB
  __shared__ unsigned short s_lds[2][16 * 40];    // stride-40 u16 rows
  __shared__ float rms_lds[32][2];
  const int tid = threadIdx.x, lane = tid & 63, wid = tid >> 6;
  const int rh = wid & 1, dh = wid >> 1;
  const int bh = blockIdx.x & 7, dvh = (blockIdx.x >> 3) & 1, p = blockIdx.x >> 4;
  const int b = bh >> 2, h = bh & 3;
  const float log2g = log2f(1.0f - exp2f(-5.0f - (float)h));
  const unsigned short* kbase = qkvg + (size_t)b * T_ * LDQKVG + E_ + h * DK;
  const unsigned short* vbase = vT + (size_t)(h * DV + dvh * 256) * MROWS + b * T_;

  auto stage = [&](int buf, int sb) {
    int s0 = sb * 32;
#pragma unroll
    for (int j = 0; j < 4; ++j) {               // K: 32 rows x 256 = 1024 chunks
      int ci = (wid * 4 + j) * 64 + lane;
      int row = ci >> 5, c = ci & 31;
      int cs = c ^ (row & 7);
      gld_lds16(kbase + (size_t)(s0 + row) * LDQKVG + cs * 8, &k_lds[buf][(wid * 4 + j) * 512]);
    }
#pragma unroll
    for (int j = 0; j < 4; ++j) {               // V: 256 dv x 32 = 1024 chunks
      int ci = (wid * 4 + j) * 64 + lane;
      int dv = ci >> 2, c = ci & 3;
      int cs = c ^ ((dv ^ (dv >> 2)) & 3);
      gld_lds16(vbase + (size_t)dv * MROWS + s0 + cs * 8, &v_lds[buf][(wid * 4 + j) * 512]);
    }
  };

#pragma unroll 1
  for (int half = 0; half < 2; ++half) {
    const int tt = half == 0 ? p : 63 - p;
    const int r0 = tt * 32;
    const int nsb = tt + 1;

    short8 qf[8];
    {
      int qrow = b * T_ + r0 + rh * 16 + (lane & 15);
      const unsigned short* qp = qkvg + (size_t)qrow * LDQKVG + h * DK + (lane >> 4) * 8;
#pragma unroll
      for (int kk = 0; kk < 8; kk++) qf[kk] = *(const short8*)(qp + kk * 32);
    }
    floatx4 oacc[8];
#pragma unroll
    for (int i = 0; i < 8; i++) oacc[i] = (floatx4){0.f, 0.f, 0.f, 0.f};

    stage(0, 0);
#pragma unroll 1
    for (int sb = 0; sb < nsb; ++sb) {
      const int cur = sb & 1;
      __syncthreads();                           // staging of cur complete
      // phase 1: S[16 rows(rh)][16 cols(dh)], K = 256
      floatx4 f = (floatx4){0.f, 0.f, 0.f, 0.f};
      const int scol_l = dh * 16 + (lane & 15);
#pragma unroll
      for (int kk = 0; kk < 8; kk++) {
        int c = (kk * 4 + (lane >> 4)) ^ (scol_l & 7);
        short8 kf = *(const short8*)&k_lds[cur][scol_l * 256 + c * 8];
        f = __builtin_amdgcn_mfma_f32_16x16x32_bf16(qf[kk], kf, f, 0, 0, 0);
      }
      const int s0 = sb * 32;
#pragma unroll
      for (int r = 0; r < 4; ++r) {
        int lr = (lane >> 4) * 4 + r;
        int qrow_h = r0 + rh * 16 + lr;
        int scol = s0 + dh * 16 + (lane & 15);
        int n = qrow_h - scol;
        float val = (n >= 0) ? f[r] * exp2f((float)n * log2g) : 0.0f;
        s_lds[rh][lr * 40 + dh * 16 + (lane & 15)] = f2bf(val);
      }
      __syncthreads();                           // S ready
      if (sb + 1 < nsb) stage(cur ^ 1, sb + 1);
      // phase 2: O[16 rows][dh*128 .. +128] += S @ V
      short8 af = *(const short8*)&s_lds[rh][(lane & 15) * 40 + (lane >> 4) * 8];
#pragma unroll
      for (int nb = 0; nb < 8; ++nb) {
        int dv = dh * 128 + nb * 16 + (lane & 15);
        int c = (lane >> 4) ^ ((dv ^ (dv >> 2)) & 3);
        short8 vf = *(const short8*)&v_lds[cur][dv * 32 + c * 8];
        oacc[nb] = __builtin_amdgcn_mfma_f32_16x16x32_bf16(af, vf, oacc[nb], 0, 0, 0);
      }
    }
    // epilogue: partial RMS (this block's 256 dv), gate, store
#pragma unroll
    for (int r = 0; r < 4; ++r) {
      float ss = 0.f;
#pragma unroll
      for (int nb = 0; nb < 8; nb++) { float xv = oacc[nb][r]; ss += xv * xv; }
      ss += __shfl_xor(ss, 1, 64);
      ss += __shfl_xor(ss, 2, 64);
      ss += __shfl_xor(ss, 4, 64);
      ss += __shfl_xor(ss, 8, 64);
      if ((lane & 15) == 0) rms_lds[rh * 16 + (lane >> 4) * 4 + r][dh] = ss;
    }
    __syncthreads();
    if (dh == 0 && (lane & 15) == 0) {
#pragma unroll
      for (int r = 0; r < 4; ++r) {
        int rl = rh * 16 + (lane >> 4) * 4 + r;
        ssbuf[(size_t)(b * T_ + r0 + rl) * 8 + h * 2 + dvh] = rms_lds[rl][0] + rms_lds[rl][1];
      }
    }
#pragma unroll
    for (int r = 0; r < 4; ++r) {
      int rl = rh * 16 + (lane >> 4) * 4 + r;
      int qrow = b * T_ + r0 + rl;
      size_t growbase = (size_t)qrow * LDQKVG + 4096 + h * DV + dvh * 256 + dh * 128;
      size_t orowbase = (size_t)qrow * LDOG + h * DV + dvh * 256 + dh * 128;
#pragma unroll
      for (int nb = 0; nb < 8; nb++) {
        int col = nb * 16 + (lane & 15);
        float gv = bf2f(qkvg[growbase + col]);
        og[orowbase + col] = f2bf(oacc[nb][r] * gnw[dvh * 256 + dh * 128 + col] * gv);
      }
    }
    __syncthreads();                             // protect LDS reuse across halves
  }
}

// ---------------- normalize og by full-row RMS ----------------
__global__ void __launch_bounds__(256) normalize_kernel(
    unsigned short* __restrict__ og, const float* __restrict__ ssbuf) {
  int i = blockIdx.x * 256 + threadIdx.x;       // one short8 per thread
  size_t e0 = (size_t)i * 8;
  int row = (int)(e0 >> 11);
  int col = (int)(e0 & 2047);
  int h = col >> 9;
  float ss = ssbuf[(size_t)row * 8 + h * 2] + ssbuf[(size_t)row * 8 + h * 2 + 1];
  float inv = rsqrtf(ss * (1.0f / 512.0f) + 1e-5f);
  short8 v = *(const short8*)(og + e0);
#pragma unroll
  for (int j = 0; j < 8; j++) v[j] = (short)f2bf(bf2f((unsigned short)v[j]) * inv);
  *(short8*)(og + e0) = v;
}

extern "C" void kernel_launch(void* const* d_in, const int* in_sizes, int n_in,
                              void* d_out, int out_size, void* d_ws, size_t ws_size,
                              hipStream_t stream) {
  const float* x   = (const float*)d_in[0];
  const float* Wq  = (const float*)d_in[1];
  const float* Wk  = (const float*)d_in[2];
  const float* Wv  = (const float*)d_in[3];
  const float* Wg  = (const float*)d_in[4];
  const float* Wo  = (const float*)d_in[5];
  const float* gnw = (const float*)d_in[6];
  float* out = (float*)d_out;

  char* ws = (char*)d_ws;
  size_t off = 0;
  auto alloc = [&](size_t bytes) { char* p = ws + off; off += (bytes + 255) & ~(size_t)255; return p; };
  unsigned short* xb    = (unsigned short*)alloc((size_t)MROWS * E_ * 2);
  unsigned short* WallT = (unsigned short*)alloc((size_t)6144 * 1024 * 2);
  unsigned short* WoT   = (unsigned short*)alloc((size_t)1024 * 2048 * 2);
  unsigned short* qkvg  = (unsigned short*)alloc((size_t)MROWS * LDQKVG * 2);
  unsigned short* vT    = (unsigned short*)alloc((size_t)2048 * MROWS * 2);
  unsigned short* og    = (unsigned short*)alloc((size_t)MROWS * LDOG * 2);
  float*          ssbuf = (float*)alloc((size_t)MROWS * 8 * 4);

  convx_kernel<<<2048, 256, 0, stream>>>(x, xb);

  transpose_bf16_kernel<float><<<dim3(32, 32), 256, 0, stream>>>(Wq, 1024, WallT, 1024);
  transpose_bf16_kernel<float><<<dim3(32, 32), 256, 0, stream>>>(Wk, 1024, WallT + (size_t)1024 * 1024, 1024);
  transpose_bf16_kernel<float><<<dim3(64, 32), 256, 0, stream>>>(Wv, 2048, WallT + (size_t)2048 * 1024, 1024);
  transpose_bf16_kernel<float><<<dim3(64, 32), 256, 0, stream>>>(Wg, 2048, WallT + (size_t)4096 * 1024, 1024);
  transpose_bf16_kernel<float><<<dim3(32, 64), 256, 0, stream>>>(Wo, 1024, WoT, 2048);

  // fused q|k|v|g projection: 4096 x 6144 x 1024
  gemm_bt_kernel<128, false><<<dim3(32, 48), 256, 0, stream>>>(xb, WallT, qkvg, 1024, LDQKVG, 0);

  rope_kernel<<<8192, 256, 0, stream>>>(qkvg);

  transpose_bf16_kernel<unsigned short><<<dim3(64, 128), 256, 0, stream>>>(qkvg + 2048, LDQKVG, vT, MROWS);

  retention_kernel<<<512, 256, 0, stream>>>(qkvg, vT, gnw, og, ssbuf);

  normalize_kernel<<<4096, 256, 0, stream>>>(og, ssbuf);

  // out: 4096 x 1024, K=2048, 64x128 tiles -> 512 blocks
  gemm_bt_kernel<64, true><<<dim3(64, 8), 256, 0, stream>>>(og, WoT, out, 2048, E_, 0);
}